// Round 1
// baseline (66.132 us; speedup 1.0000x reference)
//
#include <hip/hip_runtime.h>
#include <hip/hip_bf16.h>

using bf16x8 = __attribute__((ext_vector_type(8))) short;
using f32x4  = __attribute__((ext_vector_type(4))) float;

#define THREADS 256
#define NBLOCKS 768
#define NTILES  31250   // 500000 / 16

__device__ __forceinline__ short f2bf(float f) {
    unsigned u = __float_as_uint(f);
    unsigned r = (u + 0x7fffu + ((u >> 16) & 1u)) >> 16;   // RNE f32->bf16
    return (short)r;
}

__device__ __forceinline__ bf16x8 cvt8(float4 a, float4 b) {
    bf16x8 r;
    r[0] = f2bf(a.x); r[1] = f2bf(a.y); r[2] = f2bf(a.z); r[3] = f2bf(a.w);
    r[4] = f2bf(b.x); r[5] = f2bf(b.y); r[6] = f2bf(b.z); r[7] = f2bf(b.w);
    return r;
}

__global__ __launch_bounds__(THREADS) void etl_kernel(
    const int*   __restrict__ bi,   // [500000,3]
    const float* __restrict__ t,    // [500000]
    const float* __restrict__ U,    // [300000,64]
    const float* __restrict__ W1,   // [193,50]
    const float* __restrict__ b1,   // [50]
    const float* __restrict__ W2,   // [50]
    const float* __restrict__ b2,   // [1]
    float*       __restrict__ out)  // [500000]
{
    // ---- build W1 bf16 B-fragments in LDS, fragment layout [nt*6+ks][lane][8]
    __shared__ short bsh[24][64][8];
    for (int e = threadIdx.x; e < 24 * 64; e += THREADS) {
        int f = e >> 6, l = e & 63;
        int nt = f / 6, ks = f - nt * 6;
        int n  = nt * 16 + (l & 15);
        int k0 = ks * 32 + ((l >> 4) << 3);
        bf16x8 v;
#pragma unroll
        for (int j = 0; j < 8; ++j) {
            float w = (n < 50) ? W1[(k0 + j) * 50 + n] : 0.f;
            v[j] = f2bf(w);
        }
        *(bf16x8*)(&bsh[f][l][0]) = v;
    }
    __syncthreads();

    const int lane = threadIdx.x & 63;
    const int g    = lane >> 4;    // 0..3
    const int ncol = lane & 15;    // n within N-tile / row within M-tile

    // hoist B fragments to registers (reused across all tiles of this wave)
    bf16x8 Bf[24];
#pragma unroll
    for (int f = 0; f < 24; ++f) Bf[f] = *(const bf16x8*)(&bsh[f][lane][0]);

    // epilogue invariants (exact fp32): t-row of W1, b1, W2 for this lane's 4 n's
    float w192[4], b1r[4], w2r[4];
#pragma unroll
    for (int nt = 0; nt < 4; ++nt) {
        int n = nt * 16 + ncol;
        bool vld = (n < 50);
        w192[nt] = vld ? W1[192 * 50 + n] : 0.f;
        b1r[nt]  = vld ? b1[n] : 0.f;
        w2r[nt]  = vld ? W2[n] : 0.f;
    }
    const float b2v = b2[0];

    const int nwaves = NBLOCKS * (THREADS / 64);
    const int wid    = blockIdx.x * (THREADS / 64) + (threadIdx.x >> 6);

    for (int tile = wid; tile < NTILES; tile += nwaves) {
        const int base = tile * 16;
        const int row  = base + ncol;   // this lane's A-row

        int i0 = bi[row * 3 + 0];
        int i1 = bi[row * 3 + 1] + 100000;
        int i2 = bi[row * 3 + 2] + 200000;

        // gather A fragments: lane (g,ncol) takes k = ks*32 + g*8 .. +7
        bf16x8 A[6];
        {
            const float* p0 = U + (size_t)i0 * 64 + g * 8;
            const float* p1 = U + (size_t)i1 * 64 + g * 8;
            const float* p2 = U + (size_t)i2 * 64 + g * 8;
            float4 a0 = ((const float4*)p0)[0], a1 = ((const float4*)p0)[1];
            float4 a2 = ((const float4*)(p0 + 32))[0], a3 = ((const float4*)(p0 + 32))[1];
            float4 b0 = ((const float4*)p1)[0], b1v4 = ((const float4*)p1)[1];
            float4 b2v4 = ((const float4*)(p1 + 32))[0], b3 = ((const float4*)(p1 + 32))[1];
            float4 c0 = ((const float4*)p2)[0], c1 = ((const float4*)p2)[1];
            float4 c2 = ((const float4*)(p2 + 32))[0], c3 = ((const float4*)(p2 + 32))[1];
            A[0] = cvt8(a0, a1);  A[1] = cvt8(a2, a3);
            A[2] = cvt8(b0, b1v4); A[3] = cvt8(b2v4, b3);
            A[4] = cvt8(c0, c1);  A[5] = cvt8(c2, c3);
        }

        f32x4 acc[4];
#pragma unroll
        for (int nt = 0; nt < 4; ++nt) acc[nt] = (f32x4){0.f, 0.f, 0.f, 0.f};

#pragma unroll
        for (int ks = 0; ks < 6; ++ks) {
#pragma unroll
            for (int nt = 0; nt < 4; ++nt) {
                acc[nt] = __builtin_amdgcn_mfma_f32_16x16x32_bf16(
                    A[ks], Bf[nt * 6 + ks], acc[nt], 0, 0, 0);
            }
        }

        // epilogue: D[m][n], m = g*4+r, n = nt*16+ncol
        float4 tv = *(const float4*)(t + base + g * 4);
        float tarr[4] = {tv.x, tv.y, tv.z, tv.w};
        float part[4] = {0.f, 0.f, 0.f, 0.f};
#pragma unroll
        for (int nt = 0; nt < 4; ++nt) {
#pragma unroll
            for (int r = 0; r < 4; ++r) {
                float pre = acc[nt][r] + tarr[r] * w192[nt] + b1r[nt];
                float e  = __expf(2.f * pre);
                float h  = 1.f - 2.f * __builtin_amdgcn_rcpf(e + 1.f);  // tanh
                part[r] += h * w2r[nt];
            }
        }
        // reduce across the 16 lanes of this g-group (lane bits 0..3)
#pragma unroll
        for (int r = 0; r < 4; ++r) {
#pragma unroll
            for (int m = 1; m < 16; m <<= 1)
                part[r] += __shfl_xor(part[r], m, 64);
        }
        if (ncol == 0) {
            float4 o = make_float4(part[0] + b2v, part[1] + b2v,
                                   part[2] + b2v, part[3] + b2v);
            *(float4*)(out + base + g * 4) = o;
        }
    }
}

extern "C" void kernel_launch(void* const* d_in, const int* in_sizes, int n_in,
                              void* d_out, int out_size, void* d_ws, size_t ws_size,
                              hipStream_t stream) {
    const int*   bi = (const int*)  d_in[0];
    const float* t  = (const float*)d_in[1];
    const float* U  = (const float*)d_in[2];
    const float* W1 = (const float*)d_in[3];
    const float* b1 = (const float*)d_in[4];
    const float* W2 = (const float*)d_in[5];
    const float* b2 = (const float*)d_in[6];
    float* out = (float*)d_out;
    etl_kernel<<<NBLOCKS, THREADS, 0, stream>>>(bi, t, U, W1, b1, W2, b2, out);
}